// Round 6
// baseline (199.596 us; speedup 1.0000x reference)
//
#include <hip/hip_runtime.h>
#include <math.h>

#define SPATIAL 262144   // 64^3
#define NVOX    1048576  // 4 * 64^3
#define NVOL    12       // 4 batches * 3 foreground classes
#define FAR_D2  50000    // sentinel: > max genuine d^2 (11907), no u16 overflow
#define NPART   13       // Tversky/focal partial values per batch
#define NBLK    (NVOL * 64)

typedef unsigned short u16x2 __attribute__((ext_vector_type(2)));
union pku { unsigned int u; u16x2 v; };

__device__ __forceinline__ unsigned int pk_min(unsigned int a, unsigned int b) {
    pku x, y; x.u = a; y.u = b;
    x.v = __builtin_elementwise_min(x.v, y.v);
    return x.u;
}
__device__ __forceinline__ unsigned int pk_max(unsigned int a, unsigned int b) {
    pku x, y; x.u = a; y.u = b;
    x.v = __builtin_elementwise_max(x.v, y.v);
    return x.u;
}

// squared distance (int) from lane i to nearest set bit in 64-bit row mask.
__device__ __forceinline__ int row_d2i(unsigned long long m, int i) {
    if (m == 0ull) return FAR_D2;
    unsigned long long right = m >> i;
    unsigned long long left  = m << (63 - i);
    int dr = right ? __builtin_ctzll(right) : 1000;
    int dl = left  ? __builtin_clzll(left)  : 1000;
    int d = (dr < dl) ? dr : dl;
    return d * d;
}

// Windowed exact packed min-plus; wave W owns i in [8W, 8W+8), lane = column.
// Skipped j satisfy d^2 >= all accumulators (both halves) -> exact.
// Bound refreshed every 8 expansion steps (stale bound only over-scans).
#define MINPLUS_PK(LA, ACC, LANE, W)                                            \
    {                                                                           \
        const int base = (W) * 8;                                               \
        _Pragma("unroll")                                                       \
        for (int jj = 0; jj < 8; ++jj) {                                        \
            unsigned int wv = LA[(base + jj) * 64 + (LANE)];                    \
            _Pragma("unroll")                                                   \
            for (int k = 0; k < 8; ++k) {                                       \
                int d = k - jj;                                                 \
                unsigned int dd = (unsigned int)(d * d);                        \
                ACC[k] = pk_min(ACC[k], wv + (dd | (dd << 16)));                \
            }                                                                   \
        }                                                                       \
        const int el_max = base, er_max = 56 - base;                            \
        int t = 1;                                                              \
        while (true) {                                                          \
            unsigned int am = 0;                                                \
            _Pragma("unroll")                                                   \
            for (int k = 0; k < 8; ++k) am = pk_max(am, ACC[k]);                \
            _Pragma("unroll")                                                   \
            for (int off = 32; off > 0; off >>= 1)                              \
                am = pk_max(am, (unsigned int)__shfl_xor((int)am, off, 64));    \
            int amx = (int)(am & 0xFFFFu), amy = (int)(am >> 16);               \
            int mm = (amx > amy) ? amx : amy;                                   \
            int dmax = (int)sqrtf((float)mm) + 1;  /* overshoot-safe bound */   \
            int Tl = (dmax < el_max) ? dmax : el_max;                           \
            int Tr = (dmax < er_max) ? dmax : er_max;                           \
            int T = (Tl > Tr) ? Tl : Tr;                                        \
            if (t > T) break;                                                   \
            int tend = (T < t + 7) ? T : (t + 7);                               \
            for (; t <= tend; ++t) {                                            \
                if (t <= Tl) {                                                  \
                    unsigned int wv = LA[(base - t) * 64 + (LANE)];             \
                    _Pragma("unroll")                                           \
                    for (int k = 0; k < 8; ++k) {                               \
                        int d = t + k;                                          \
                        unsigned int dd = (unsigned int)(d * d);                \
                        ACC[k] = pk_min(ACC[k], wv + (dd | (dd << 16)));        \
                    }                                                           \
                }                                                               \
                if (t <= Tr) {                                                  \
                    unsigned int wv = LA[(base + 7 + t) * 64 + (LANE)];         \
                    _Pragma("unroll")                                           \
                    for (int k = 0; k < 8; ++k) {                               \
                        int d = t + 7 - k;                                      \
                        unsigned int dd = (unsigned int)(d * d);                \
                        ACC[k] = pk_min(ACC[k], wv + (dd | (dd << 16)));        \
                    }                                                           \
                }                                                               \
            }                                                                   \
        }                                                                       \
    }

// Fused x-DT (ballot, both fields packed) + windowed y-DT for one (v,z) slice.
// Block 0 also zeroes the finalize ticket (visible to the next kernel by
// stream ordering -- same guarantee dtp relies on).
__global__ __launch_bounds__(512) void dtxy_kernel(
        const int* __restrict__ targets, unsigned int* __restrict__ dtp,
        unsigned int* __restrict__ counter) {
    __shared__ unsigned int la[4096];
    int blk = blockIdx.x;
    if (blk == 0 && threadIdx.x == 0) *counter = 0u;
    int v = blk >> 6, z = blk & 63;
    int b = v / 3, cls = (v % 3) + 1;
    const int* tp = targets + b * SPATIAL + z * 4096;
    int t = threadIdx.x, lane = t & 63, w = t >> 6;   // w in [0,8)

    #pragma unroll
    for (int k = 0; k < 8; ++k) {
        int y = w * 8 + k;
        int tv = tp[y * 64 + lane];
        unsigned long long m = __ballot(tv == cls);
        int do2 = row_d2i(m, lane);
        int di2 = row_d2i(~m, lane);
        la[y * 64 + lane] = (unsigned int)do2 | ((unsigned int)di2 << 16);
    }
    __syncthreads();

    unsigned int acc[8];
    #pragma unroll
    for (int k = 0; k < 8; ++k) acc[k] = 0xFFFFFFFFu;
    MINPLUS_PK(la, acc, lane, w)

    size_t vol = (size_t)v * SPATIAL;
    #pragma unroll
    for (int k = 0; k < 8; ++k) {
        int i = w * 8 + k;
        dtp[vol + (size_t)z * 4096 + (size_t)i * 64 + lane] = acc[k];
    }
}

// Windowed z-DT (packed) + sdf + softmax + boundary partial; cls==1 blocks
// additionally accumulate the 13 Tversky/focal quantities for their batch.
// Last block to finish (device ticket) reduces all partials and writes out.
__global__ __launch_bounds__(512) void dtz_fused_kernel(
        const unsigned int* __restrict__ dtp, const float* __restrict__ preds,
        const int* __restrict__ targets,
        float* __restrict__ bound, float* __restrict__ rpart,
        unsigned int* __restrict__ counter, float* __restrict__ out) {
    __shared__ unsigned int la[4096];
    int blk = blockIdx.x;
    int v = blk >> 6, y = blk & 63;
    int b = v / 3, cls = (v % 3) + 1;
    size_t vol = (size_t)v * SPATIAL;
    int t = threadIdx.x, lane = t & 63, w = t >> 6;   // w in [0,8)

    // Vectorized staging: 2 x uint4 per thread; 16 threads per (zz) row.
    #pragma unroll
    for (int r = 0; r < 2; ++r) {
        int zz = r * 32 + (t >> 4);
        int x4 = (t & 15) << 2;
        uint4 q = *(const uint4*)(dtp + vol + (size_t)zz * 4096 + ((size_t)y << 6) + x4);
        *(uint4*)(&la[zz * 64 + x4]) = q;
    }
    __syncthreads();

    unsigned int acc[8];
    #pragma unroll
    for (int k = 0; k < 8; ++k) acc[k] = 0xFFFFFFFFu;
    MINPLUS_PK(la, acc, lane, w)

    const bool doRed = (cls == 1);   // block-uniform
    float loc[NPART];
    #pragma unroll
    for (int k = 0; k < NPART; ++k) loc[k] = 0.0f;

    float partial = 0.0f;
    const float* pbase = preds + (size_t)b * 4 * SPATIAL;
    const int* tbase = targets + b * SPATIAL;
    #pragma unroll
    for (int k = 0; k < 8; ++k) {
        int i = w * 8 + k;  // z coordinate
        size_t sp = (size_t)i * 4096 + (size_t)y * 64 + lane;
        float dout = (float)(acc[k] & 0xFFFFu);
        float din  = (float)(acc[k] >> 16);
        float sv = sqrtf(dout) - sqrtf(din);
        float p0 = pbase[sp], p1 = pbase[SPATIAL + sp];
        float p2 = pbase[2 * SPATIAL + sp], p3 = pbase[3 * SPATIAL + sp];
        float m = fmaxf(fmaxf(p0, p1), fmaxf(p2, p3));
        float e0 = __expf(p0 - m), e1 = __expf(p1 - m);
        float e2 = __expf(p2 - m), e3 = __expf(p3 - m);
        float s = e0 + e1 + e2 + e3;
        float inv = __builtin_amdgcn_rcpf(s);
        float ec = (cls == 1) ? e1 : (cls == 2) ? e2 : e3;
        partial += sv * (ec * inv);
        if (doRed) {
            int tv = tbase[sp];
            float q0 = e0 * inv, q1 = e1 * inv, q2 = e2 * inv, q3 = e3 * inv;
            float pl = (tv == 0) ? p0 : (tv == 1) ? p1 : (tv == 2) ? p2 : p3;
            float ce = __logf(s) + (m - pl);           // lse - pl
            float qt = (tv == 0) ? q0 : (tv == 1) ? q1 : (tv == 2) ? q2 : q3;
            float om = 1.0f - qt;
            loc[0] += q0; loc[1] += q1; loc[2] += q2; loc[3] += q3;
            if (tv == 0)      { loc[4] += q0; loc[8]  += 1.f; }
            else if (tv == 1) { loc[5] += q1; loc[9]  += 1.f; }
            else if (tv == 2) { loc[6] += q2; loc[10] += 1.f; }
            else              { loc[7] += q3; loc[11] += 1.f; }
            loc[12] += om * om * ce;
        }
    }

    #pragma unroll
    for (int off = 32; off > 0; off >>= 1)
        partial += __shfl_down(partial, off, 64);
    __shared__ float ws8[8];
    if (lane == 0) ws8[w] = partial;

    if (doRed) {
        __shared__ float sred[NPART][8];
        #pragma unroll
        for (int k = 0; k < NPART; ++k) {
            float vv = loc[k];
            #pragma unroll
            for (int off = 32; off > 0; off >>= 1)
                vv += __shfl_down(vv, off, 64);
            loc[k] = vv;
        }
        if (lane == 0) {
            #pragma unroll
            for (int k = 0; k < NPART; ++k) sred[k][w] = loc[k];
        }
        __syncthreads();
        if (t < NPART) {
            float tot = 0.0f;
            #pragma unroll
            for (int i = 0; i < 8; ++i) tot += sred[t][i];
            rpart[(b * NPART + t) * 64 + y] = tot;
        }
    } else {
        __syncthreads();
    }
    if (t == 0) {
        float tot = 0.0f;
        #pragma unroll
        for (int i = 0; i < 8; ++i) tot += ws8[i];
        bound[blk] = tot;   // blk = v*64 + y
    }

    // ---- last-block finalize ----
    __threadfence();
    __syncthreads();
    __shared__ unsigned int isLast;
    if (t == 0) {
        unsigned int old = atomicAdd(counter, 1u);
        isLast = (old == (unsigned int)(NBLK - 1)) ? 1u : 0u;
    }
    __syncthreads();
    if (!isLast) return;

    __shared__ float rowsum[52];
    __shared__ float bsum[12];
    for (int r = w; r < 52; r += 8) {
        float vv = rpart[r * 64 + lane];
        #pragma unroll
        for (int off = 32; off > 0; off >>= 1)
            vv += __shfl_down(vv, off, 64);
        if (lane == 0) rowsum[r] = vv;
    }
    for (int r = w; r < 12; r += 8) {
        float vv = bound[r * 64 + lane];
        #pragma unroll
        for (int off = 32; off > 0; off >>= 1)
            vv += __shfl_down(vv, off, 64);
        if (lane == 0) bsum[r] = vv;
    }
    __syncthreads();
    if (t != 0) return;

    float tsum = 0.0f;
    for (int bb = 0; bb < 4; ++bb)
        for (int c = 0; c < 4; ++c) {
            float S  = rowsum[bb * NPART + c];
            float TP = rowsum[bb * NPART + 4 + c];
            float CN = rowsum[bb * NPART + 8 + c];
            float FP = S - TP;
            float FN = CN - TP;
            tsum += (TP + 1e-5f) / (TP + 0.3f * FP + 0.7f * FN + 1e-5f);
        }
    float l_dice = 1.0f - tsum / 16.0f;
    float l_main = (rowsum[12] + rowsum[NPART + 12] +
                    rowsum[2 * NPART + 12] + rowsum[3 * NPART + 12]) / (float)NVOX;
    float bs = 0.0f;
    for (int vv = 0; vv < NVOL; ++vv) {
        int bb = vv / 3, c = (vv % 3) + 1;
        float CN = rowsum[bb * NPART + 8 + c];
        float contrib;
        if (CN <= 0.0f) contrib = 0.0f;
        else if (CN >= (float)SPATIAL) contrib = -rowsum[bb * NPART + c] / (float)SPATIAL;
        else contrib = bsum[vv] / (float)SPATIAL;
        bs += contrib;
    }
    float l_bound = bs / (12.0f + 1e-8f);
    out[0] = l_dice + l_main + 0.01f * l_bound;
}

extern "C" void kernel_launch(void* const* d_in, const int* in_sizes, int n_in,
                              void* d_out, int out_size, void* d_ws, size_t ws_size,
                              hipStream_t stream) {
    const float* preds = (const float*)d_in[0];
    const int* targets = (const int*)d_in[1];
    float* out = (float*)d_out;
    float* ws = (float*)d_ws;
    float* rpart = ws;                                  // 4*13*64 = 3328 floats
    float* bound = ws + 4 * NPART * 64;                 // 768 floats -> 4096 total
    unsigned int* counter = (unsigned int*)(ws + 4096); // 1 uint (+15 pad)
    unsigned int* dtp = (unsigned int*)(ws + 4112);     // 12 MB, 16B-aligned

    hipLaunchKernelGGL(dtxy_kernel, dim3(NBLK), dim3(512), 0, stream,
                       targets, dtp, counter);
    hipLaunchKernelGGL(dtz_fused_kernel, dim3(NBLK), dim3(512), 0, stream,
                       dtp, preds, targets, bound, rpart, counter, out);
}

// Round 7
// 116.255 us; speedup vs baseline: 1.7169x; 1.7169x over previous
//
#include <hip/hip_runtime.h>
#include <math.h>

#define SPATIAL 262144   // 64^3
#define NVOX    1048576  // 4 * 64^3
#define NVOL    12       // 4 batches * 3 foreground classes
#define FAR_D2  50000    // sentinel: > max genuine d^2 (11907), no u16 overflow
#define NPART   13       // Tversky/focal partial values
#define NBLK    (NVOL * 64)

typedef unsigned short u16x2 __attribute__((ext_vector_type(2)));
union pku { unsigned int u; u16x2 v; };

__device__ __forceinline__ unsigned int pk_min(unsigned int a, unsigned int b) {
    pku x, y; x.u = a; y.u = b;
    x.v = __builtin_elementwise_min(x.v, y.v);
    return x.u;
}
__device__ __forceinline__ unsigned int pk_max(unsigned int a, unsigned int b) {
    pku x, y; x.u = a; y.u = b;
    x.v = __builtin_elementwise_max(x.v, y.v);
    return x.u;
}

// squared distance (int) from lane i to nearest set bit in 64-bit row mask.
__device__ __forceinline__ int row_d2i(unsigned long long m, int i) {
    if (m == 0ull) return FAR_D2;
    unsigned long long right = m >> i;
    unsigned long long left  = m << (63 - i);
    int dr = right ? __builtin_ctzll(right) : 1000;
    int dl = left  ? __builtin_clzll(left)  : 1000;
    int d = (dr < dl) ? dr : dl;
    return d * d;
}

// Windowed exact packed min-plus; wave W owns i in [8W, 8W+8), lane = column.
// Skipped j satisfy d^2 >= all accumulators (both halves) -> exact.
#define MINPLUS_PK(LA, ACC, LANE, W)                                            \
    {                                                                           \
        const int base = (W) * 8;                                               \
        _Pragma("unroll")                                                       \
        for (int jj = 0; jj < 8; ++jj) {                                        \
            unsigned int wv = LA[(base + jj) * 64 + (LANE)];                    \
            _Pragma("unroll")                                                   \
            for (int k = 0; k < 8; ++k) {                                       \
                int d = k - jj;                                                 \
                unsigned int dd = (unsigned int)(d * d);                        \
                ACC[k] = pk_min(ACC[k], wv + (dd | (dd << 16)));                \
            }                                                                   \
        }                                                                       \
        const int el_max = base, er_max = 56 - base;                            \
        int t = 1;                                                              \
        while (true) {                                                          \
            unsigned int am = 0;                                                \
            _Pragma("unroll")                                                   \
            for (int k = 0; k < 8; ++k) am = pk_max(am, ACC[k]);                \
            _Pragma("unroll")                                                   \
            for (int off = 32; off > 0; off >>= 1)                              \
                am = pk_max(am, (unsigned int)__shfl_xor((int)am, off, 64));    \
            int amx = (int)(am & 0xFFFFu), amy = (int)(am >> 16);               \
            int mm = (amx > amy) ? amx : amy;                                   \
            int dmax = (int)sqrtf((float)mm) + 1;  /* overshoot-safe bound */   \
            int Tl = (dmax < el_max) ? dmax : el_max;                           \
            int Tr = (dmax < er_max) ? dmax : er_max;                           \
            int T = (Tl > Tr) ? Tl : Tr;                                        \
            if (t > T) break;                                                   \
            int tend = (T < t + 7) ? T : (t + 7);                               \
            for (; t <= tend; ++t) {                                            \
                if (t <= Tl) {                                                  \
                    unsigned int wv = LA[(base - t) * 64 + (LANE)];             \
                    _Pragma("unroll")                                           \
                    for (int k = 0; k < 8; ++k) {                               \
                        int d = t + k;                                          \
                        unsigned int dd = (unsigned int)(d * d);                \
                        ACC[k] = pk_min(ACC[k], wv + (dd | (dd << 16)));        \
                    }                                                           \
                }                                                               \
                if (t <= Tr) {                                                  \
                    unsigned int wv = LA[(base + 7 + t) * 64 + (LANE)];         \
                    _Pragma("unroll")                                           \
                    for (int k = 0; k < 8; ++k) {                               \
                        int d = t + 7 - k;                                      \
                        unsigned int dd = (unsigned int)(d * d);                \
                        ACC[k] = pk_min(ACC[k], wv + (dd | (dd << 16)));        \
                    }                                                           \
                }                                                               \
            }                                                                   \
        }                                                                       \
    }

// Fused x-DT (ballot, both fields packed) + windowed y-DT for one (v,z) slice.
__global__ __launch_bounds__(512) void dtxy_kernel(
        const int* __restrict__ targets, unsigned int* __restrict__ dtp) {
    __shared__ unsigned int la[4096];
    int blk = blockIdx.x;
    int v = blk >> 6, z = blk & 63;
    int b = v / 3, cls = (v % 3) + 1;
    const int* tp = targets + b * SPATIAL + z * 4096;
    int t = threadIdx.x, lane = t & 63, w = t >> 6;   // w in [0,8)

    #pragma unroll
    for (int k = 0; k < 8; ++k) {
        int y = w * 8 + k;
        int tv = tp[y * 64 + lane];
        unsigned long long m = __ballot(tv == cls);
        int do2 = row_d2i(m, lane);
        int di2 = row_d2i(~m, lane);
        la[y * 64 + lane] = (unsigned int)do2 | ((unsigned int)di2 << 16);
    }
    __syncthreads();

    unsigned int acc[8];
    #pragma unroll
    for (int k = 0; k < 8; ++k) acc[k] = 0xFFFFFFFFu;
    MINPLUS_PK(la, acc, lane, w)

    size_t vol = (size_t)v * SPATIAL;
    #pragma unroll
    for (int k = 0; k < 8; ++k) {
        int i = w * 8 + k;
        dtp[vol + (size_t)z * 4096 + (size_t)i * 64 + lane] = acc[k];
    }
}

// Windowed z-DT (packed) + sdf + softmax + boundary partial. Tversky/focal
// fold is balanced across the 3 class-volumes of each batch by z-partition:
// cls1 -> z in [0,22), cls2 -> [22,43), cls3 -> [43,64). Guard is wave-uniform.
__global__ __launch_bounds__(512) void dtz_fused_kernel(
        const unsigned int* __restrict__ dtp, const float* __restrict__ preds,
        const int* __restrict__ targets,
        float* __restrict__ bound, float* __restrict__ rpart) {
    __shared__ unsigned int la[4096];
    int blk = blockIdx.x;
    int v = blk >> 6, y = blk & 63;
    int b = v / 3, cls = (v % 3) + 1;
    size_t vol = (size_t)v * SPATIAL;
    int t = threadIdx.x, lane = t & 63, w = t >> 6;   // w in [0,8)

    // Vectorized staging: 2 x uint4 per thread; 16 threads per (zz) row.
    #pragma unroll
    for (int r = 0; r < 2; ++r) {
        int zz = r * 32 + (t >> 4);
        int x4 = (t & 15) << 2;
        uint4 q = *(const uint4*)(dtp + vol + (size_t)zz * 4096 + ((size_t)y << 6) + x4);
        *(uint4*)(&la[zz * 64 + x4]) = q;
    }
    __syncthreads();

    unsigned int acc[8];
    #pragma unroll
    for (int k = 0; k < 8; ++k) acc[k] = 0xFFFFFFFFu;
    MINPLUS_PK(la, acc, lane, w)

    const int zlo = (cls == 1) ? 0 : (cls == 2) ? 22 : 43;
    const int zhi = (cls == 1) ? 22 : (cls == 2) ? 43 : 64;

    float loc[NPART];
    #pragma unroll
    for (int k = 0; k < NPART; ++k) loc[k] = 0.0f;

    float partial = 0.0f;
    const float* pbase = preds + (size_t)b * 4 * SPATIAL;
    const int* tbase = targets + b * SPATIAL;
    #pragma unroll
    for (int k = 0; k < 8; ++k) {
        int i = w * 8 + k;  // z coordinate
        size_t sp = (size_t)i * 4096 + (size_t)y * 64 + lane;
        float dout = (float)(acc[k] & 0xFFFFu);
        float din  = (float)(acc[k] >> 16);
        float sv = sqrtf(dout) - sqrtf(din);
        float p0 = pbase[sp], p1 = pbase[SPATIAL + sp];
        float p2 = pbase[2 * SPATIAL + sp], p3 = pbase[3 * SPATIAL + sp];
        float m = fmaxf(fmaxf(p0, p1), fmaxf(p2, p3));
        float e0 = __expf(p0 - m), e1 = __expf(p1 - m);
        float e2 = __expf(p2 - m), e3 = __expf(p3 - m);
        float s = e0 + e1 + e2 + e3;
        float inv = __builtin_amdgcn_rcpf(s);
        float ec = (cls == 1) ? e1 : (cls == 2) ? e2 : e3;
        partial += sv * (ec * inv);
        if (i >= zlo && i < zhi) {   // wave-uniform per k
            int tv = tbase[sp];
            float q0 = e0 * inv, q1 = e1 * inv, q2 = e2 * inv, q3 = e3 * inv;
            float pl = (tv == 0) ? p0 : (tv == 1) ? p1 : (tv == 2) ? p2 : p3;
            float ce = __logf(s) + (m - pl);           // lse - pl
            float qt = (tv == 0) ? q0 : (tv == 1) ? q1 : (tv == 2) ? q2 : q3;
            float om = 1.0f - qt;
            loc[0] += q0; loc[1] += q1; loc[2] += q2; loc[3] += q3;
            if (tv == 0)      { loc[4] += q0; loc[8]  += 1.f; }
            else if (tv == 1) { loc[5] += q1; loc[9]  += 1.f; }
            else if (tv == 2) { loc[6] += q2; loc[10] += 1.f; }
            else              { loc[7] += q3; loc[11] += 1.f; }
            loc[12] += om * om * ce;
        }
    }

    #pragma unroll
    for (int off = 32; off > 0; off >>= 1)
        partial += __shfl_down(partial, off, 64);
    __shared__ float ws8[8];
    if (lane == 0) ws8[w] = partial;

    __shared__ float sred[NPART][8];
    #pragma unroll
    for (int k = 0; k < NPART; ++k) {
        float vv = loc[k];
        #pragma unroll
        for (int off = 32; off > 0; off >>= 1)
            vv += __shfl_down(vv, off, 64);
        loc[k] = vv;
    }
    if (lane == 0) {
        #pragma unroll
        for (int k = 0; k < NPART; ++k) sred[k][w] = loc[k];
    }
    __syncthreads();
    if (t < NPART) {
        float tot = 0.0f;
        #pragma unroll
        for (int i = 0; i < 8; ++i) tot += sred[t][i];
        rpart[(v * NPART + t) * 64 + y] = tot;
    }
    if (t == 0) {
        float tot = 0.0f;
        #pragma unroll
        for (int i = 0; i < 8; ++i) tot += ws8[i];
        bound[blk] = tot;   // blk = v*64 + y
    }
}

// Single block: reduce 12x13x64 Tversky/focal partials + 12x64 bound partials.
__global__ __launch_bounds__(256) void final_kernel(
        const float* __restrict__ rpart, const float* __restrict__ bound,
        float* __restrict__ out) {
    __shared__ float rowsum[NVOL * NPART];   // per-volume sums over y
    __shared__ float bsum[NVOL];
    int tid = threadIdx.x, lane = tid & 63, w = tid >> 6;

    for (int r = w; r < NVOL * NPART; r += 4) {
        float v = rpart[r * 64 + lane];
        #pragma unroll
        for (int off = 32; off > 0; off >>= 1)
            v += __shfl_down(v, off, 64);
        if (lane == 0) rowsum[r] = v;
    }
    for (int r = w; r < NVOL; r += 4) {
        float v = bound[r * 64 + lane];
        #pragma unroll
        for (int off = 32; off > 0; off >>= 1)
            v += __shfl_down(v, off, 64);
        if (lane == 0) bsum[r] = v;
    }
    __syncthreads();
    if (tid != 0) return;

    // per-batch totals = sum over the batch's 3 volumes (z-partitioned)
    float tsum = 0.0f;
    float Sb[4][4], CNb[4][4];
    for (int b = 0; b < 4; ++b)
        for (int c = 0; c < 4; ++c) {
            float S = 0.f, TP = 0.f, CN = 0.f;
            for (int vi = 0; vi < 3; ++vi) {
                const float* rs = rowsum + (b * 3 + vi) * NPART;
                S  += rs[c];
                TP += rs[4 + c];
                CN += rs[8 + c];
            }
            Sb[b][c] = S; CNb[b][c] = CN;
            float FP = S - TP;
            float FN = CN - TP;
            tsum += (TP + 1e-5f) / (TP + 0.3f * FP + 0.7f * FN + 1e-5f);
        }
    float l_dice = 1.0f - tsum / 16.0f;
    float fsum = 0.0f;
    for (int v = 0; v < NVOL; ++v) fsum += rowsum[v * NPART + 12];
    float l_main = fsum / (float)NVOX;
    float bs = 0.0f;
    for (int v = 0; v < NVOL; ++v) {
        int b = v / 3, c = (v % 3) + 1;
        float CN = CNb[b][c];
        float contrib;
        if (CN <= 0.0f) contrib = 0.0f;
        else if (CN >= (float)SPATIAL) contrib = -Sb[b][c] / (float)SPATIAL;
        else contrib = bsum[v] / (float)SPATIAL;
        bs += contrib;
    }
    float l_bound = bs / (12.0f + 1e-8f);
    out[0] = l_dice + l_main + 0.01f * l_bound;
}

extern "C" void kernel_launch(void* const* d_in, const int* in_sizes, int n_in,
                              void* d_out, int out_size, void* d_ws, size_t ws_size,
                              hipStream_t stream) {
    const float* preds = (const float*)d_in[0];
    const int* targets = (const int*)d_in[1];
    float* out = (float*)d_out;
    float* ws = (float*)d_ws;
    float* rpart = ws;                                  // 12*13*64 = 9984 floats
    float* bound = ws + NVOL * NPART * 64;              // 768 floats -> 10752 total
    unsigned int* dtp = (unsigned int*)(ws + 10752);    // 12 MB, 16B-aligned

    hipLaunchKernelGGL(dtxy_kernel, dim3(NBLK), dim3(512), 0, stream,
                       targets, dtp);
    hipLaunchKernelGGL(dtz_fused_kernel, dim3(NBLK), dim3(512), 0, stream,
                       dtp, preds, targets, bound, rpart);
    hipLaunchKernelGGL(final_kernel, dim3(1), dim3(256), 0, stream,
                       rpart, bound, out);
}

// Round 8
// 102.839 us; speedup vs baseline: 1.9409x; 1.1305x over previous
//
#include <hip/hip_runtime.h>
#include <math.h>

#define SPATIAL 262144   // 64^3
#define NVOX    1048576  // 4 * 64^3
#define NVOL    12       // 4 batches * 3 foreground classes
#define FAR_D2  50000    // sentinel: > max genuine d^2 (11907), no u16 overflow
#define NPART   13       // Tversky/focal partial values per batch
#define NBLK    (NVOL * 64)

typedef unsigned short u16x2 __attribute__((ext_vector_type(2)));
union pku { unsigned int u; u16x2 v; };

__device__ __forceinline__ unsigned int pk_min(unsigned int a, unsigned int b) {
    pku x, y; x.u = a; y.u = b;
    x.v = __builtin_elementwise_min(x.v, y.v);
    return x.u;
}
__device__ __forceinline__ unsigned int pk_max(unsigned int a, unsigned int b) {
    pku x, y; x.u = a; y.u = b;
    x.v = __builtin_elementwise_max(x.v, y.v);
    return x.u;
}

// squared distance (int) from lane i to nearest set bit in 64-bit row mask.
__device__ __forceinline__ int row_d2i(unsigned long long m, int i) {
    if (m == 0ull) return FAR_D2;
    unsigned long long right = m >> i;
    unsigned long long left  = m << (63 - i);
    int dr = right ? __builtin_ctzll(right) : 1000;
    int dl = left  ? __builtin_clzll(left)  : 1000;
    int d = (dr < dl) ? dr : dl;
    return d * d;
}

// Windowed exact packed min-plus; wave W owns i in [8W, 8W+8), lane = column.
// Skipped j satisfy d^2 >= all accumulators (both halves) -> exact.
// Bound refreshed every 8 expansion steps (stale bound only over-scans).
#define MINPLUS_PK(LA, ACC, LANE, W)                                            \
    {                                                                           \
        const int base = (W) * 8;                                               \
        _Pragma("unroll")                                                       \
        for (int jj = 0; jj < 8; ++jj) {                                        \
            unsigned int wv = LA[(base + jj) * 64 + (LANE)];                    \
            _Pragma("unroll")                                                   \
            for (int k = 0; k < 8; ++k) {                                       \
                int d = k - jj;                                                 \
                unsigned int dd = (unsigned int)(d * d);                        \
                ACC[k] = pk_min(ACC[k], wv + (dd | (dd << 16)));                \
            }                                                                   \
        }                                                                       \
        const int el_max = base, er_max = 56 - base;                            \
        int t = 1;                                                              \
        while (true) {                                                          \
            unsigned int am = 0;                                                \
            _Pragma("unroll")                                                   \
            for (int k = 0; k < 8; ++k) am = pk_max(am, ACC[k]);                \
            _Pragma("unroll")                                                   \
            for (int off = 32; off > 0; off >>= 1)                              \
                am = pk_max(am, (unsigned int)__shfl_xor((int)am, off, 64));    \
            int amx = (int)(am & 0xFFFFu), amy = (int)(am >> 16);               \
            int mm = (amx > amy) ? amx : amy;                                   \
            int dmax = (int)sqrtf((float)mm) + 1;  /* overshoot-safe bound */   \
            int Tl = (dmax < el_max) ? dmax : el_max;                           \
            int Tr = (dmax < er_max) ? dmax : er_max;                           \
            int T = (Tl > Tr) ? Tl : Tr;                                        \
            if (t > T) break;                                                   \
            int tend = (T < t + 7) ? T : (t + 7);                               \
            for (; t <= tend; ++t) {                                            \
                if (t <= Tl) {                                                  \
                    unsigned int wv = LA[(base - t) * 64 + (LANE)];             \
                    _Pragma("unroll")                                           \
                    for (int k = 0; k < 8; ++k) {                               \
                        int d = t + k;                                          \
                        unsigned int dd = (unsigned int)(d * d);                \
                        ACC[k] = pk_min(ACC[k], wv + (dd | (dd << 16)));        \
                    }                                                           \
                }                                                               \
                if (t <= Tr) {                                                  \
                    unsigned int wv = LA[(base + 7 + t) * 64 + (LANE)];         \
                    _Pragma("unroll")                                           \
                    for (int k = 0; k < 8; ++k) {                               \
                        int d = t + 7 - k;                                      \
                        unsigned int dd = (unsigned int)(d * d);                \
                        ACC[k] = pk_min(ACC[k], wv + (dd | (dd << 16)));        \
                    }                                                           \
                }                                                               \
            }                                                                   \
        }                                                                       \
    }

// Fused x-DT (ballot, both fields packed) + windowed y-DT for one (v,z) slice.
__global__ __launch_bounds__(512) void dtxy_kernel(
        const int* __restrict__ targets, unsigned int* __restrict__ dtp) {
    __shared__ unsigned int la[4096];
    int blk = blockIdx.x;
    int v = blk >> 6, z = blk & 63;
    int b = v / 3, cls = (v % 3) + 1;
    const int* tp = targets + b * SPATIAL + z * 4096;
    int t = threadIdx.x, lane = t & 63, w = t >> 6;   // w in [0,8)

    #pragma unroll
    for (int k = 0; k < 8; ++k) {
        int y = w * 8 + k;
        int tv = tp[y * 64 + lane];
        unsigned long long m = __ballot(tv == cls);
        int do2 = row_d2i(m, lane);
        int di2 = row_d2i(~m, lane);
        la[y * 64 + lane] = (unsigned int)do2 | ((unsigned int)di2 << 16);
    }
    __syncthreads();

    unsigned int acc[8];
    #pragma unroll
    for (int k = 0; k < 8; ++k) acc[k] = 0xFFFFFFFFu;
    MINPLUS_PK(la, acc, lane, w)

    size_t vol = (size_t)v * SPATIAL;
    #pragma unroll
    for (int k = 0; k < 8; ++k) {
        int i = w * 8 + k;
        dtp[vol + (size_t)z * 4096 + (size_t)i * 64 + lane] = acc[k];
    }
}

// Windowed z-DT (packed) + sdf + softmax + boundary partial; cls==1 blocks
// additionally accumulate the 13 Tversky/focal quantities for their batch
// (each batch's 64 cls-1 blocks tile the volume exactly once).
// NOTE (R7 lesson): concentrating the fold in the 256 cls==1 blocks beats
// spreading it across all 768 -- per-block epilogue fixed cost dominates.
__global__ __launch_bounds__(512) void dtz_fused_kernel(
        const unsigned int* __restrict__ dtp, const float* __restrict__ preds,
        const int* __restrict__ targets,
        float* __restrict__ bound, float* __restrict__ rpart) {
    __shared__ unsigned int la[4096];
    int blk = blockIdx.x;
    int v = blk >> 6, y = blk & 63;
    int b = v / 3, cls = (v % 3) + 1;
    size_t vol = (size_t)v * SPATIAL;
    int t = threadIdx.x, lane = t & 63, w = t >> 6;   // w in [0,8)

    // Vectorized staging: 2 x uint4 per thread; 16 threads per (zz) row.
    #pragma unroll
    for (int r = 0; r < 2; ++r) {
        int zz = r * 32 + (t >> 4);
        int x4 = (t & 15) << 2;
        uint4 q = *(const uint4*)(dtp + vol + (size_t)zz * 4096 + ((size_t)y << 6) + x4);
        *(uint4*)(&la[zz * 64 + x4]) = q;
    }
    __syncthreads();

    unsigned int acc[8];
    #pragma unroll
    for (int k = 0; k < 8; ++k) acc[k] = 0xFFFFFFFFu;
    MINPLUS_PK(la, acc, lane, w)

    const bool doRed = (cls == 1);   // block-uniform
    float loc[NPART];
    #pragma unroll
    for (int k = 0; k < NPART; ++k) loc[k] = 0.0f;

    float partial = 0.0f;
    const float* pbase = preds + (size_t)b * 4 * SPATIAL;
    const int* tbase = targets + b * SPATIAL;
    #pragma unroll
    for (int k = 0; k < 8; ++k) {
        int i = w * 8 + k;  // z coordinate
        size_t sp = (size_t)i * 4096 + (size_t)y * 64 + lane;
        float dout = (float)(acc[k] & 0xFFFFu);
        float din  = (float)(acc[k] >> 16);
        float sv = sqrtf(dout) - sqrtf(din);
        float p0 = pbase[sp], p1 = pbase[SPATIAL + sp];
        float p2 = pbase[2 * SPATIAL + sp], p3 = pbase[3 * SPATIAL + sp];
        float m = fmaxf(fmaxf(p0, p1), fmaxf(p2, p3));
        float e0 = __expf(p0 - m), e1 = __expf(p1 - m);
        float e2 = __expf(p2 - m), e3 = __expf(p3 - m);
        float s = e0 + e1 + e2 + e3;
        float inv = __builtin_amdgcn_rcpf(s);
        float ec = (cls == 1) ? e1 : (cls == 2) ? e2 : e3;
        partial += sv * (ec * inv);
        if (doRed) {
            int tv = tbase[sp];
            float q0 = e0 * inv, q1 = e1 * inv, q2 = e2 * inv, q3 = e3 * inv;
            float pl = (tv == 0) ? p0 : (tv == 1) ? p1 : (tv == 2) ? p2 : p3;
            float ce = __logf(s) + (m - pl);           // lse - pl
            float qt = (tv == 0) ? q0 : (tv == 1) ? q1 : (tv == 2) ? q2 : q3;
            float om = 1.0f - qt;
            loc[0] += q0; loc[1] += q1; loc[2] += q2; loc[3] += q3;
            if (tv == 0)      { loc[4] += q0; loc[8]  += 1.f; }
            else if (tv == 1) { loc[5] += q1; loc[9]  += 1.f; }
            else if (tv == 2) { loc[6] += q2; loc[10] += 1.f; }
            else              { loc[7] += q3; loc[11] += 1.f; }
            loc[12] += om * om * ce;
        }
    }

    #pragma unroll
    for (int off = 32; off > 0; off >>= 1)
        partial += __shfl_down(partial, off, 64);
    __shared__ float ws8[8];
    if (lane == 0) ws8[w] = partial;

    if (doRed) {
        __shared__ float sred[NPART][8];
        #pragma unroll
        for (int k = 0; k < NPART; ++k) {
            float vv = loc[k];
            #pragma unroll
            for (int off = 32; off > 0; off >>= 1)
                vv += __shfl_down(vv, off, 64);
            loc[k] = vv;
        }
        if (lane == 0) {
            #pragma unroll
            for (int k = 0; k < NPART; ++k) sred[k][w] = loc[k];
        }
        __syncthreads();
        if (t < NPART) {
            float tot = 0.0f;
            #pragma unroll
            for (int i = 0; i < 8; ++i) tot += sred[t][i];
            rpart[(b * NPART + t) * 64 + y] = tot;
        }
    } else {
        __syncthreads();
    }
    if (t == 0) {
        float tot = 0.0f;
        #pragma unroll
        for (int i = 0; i < 8; ++i) tot += ws8[i];
        bound[blk] = tot;   // blk = v*64 + y
    }
}

// Single block: reduce 52x64 Tversky/focal partials + 12x64 bound partials.
__global__ __launch_bounds__(256) void final_kernel(
        const float* __restrict__ rpart, const float* __restrict__ bound,
        float* __restrict__ out) {
    __shared__ float rowsum[52];
    __shared__ float bsum[12];
    int tid = threadIdx.x, lane = tid & 63, w = tid >> 6;

    for (int r = w; r < 52; r += 4) {
        float v = rpart[r * 64 + lane];
        #pragma unroll
        for (int off = 32; off > 0; off >>= 1)
            v += __shfl_down(v, off, 64);
        if (lane == 0) rowsum[r] = v;
    }
    for (int r = w; r < 12; r += 4) {
        float v = bound[r * 64 + lane];
        #pragma unroll
        for (int off = 32; off > 0; off >>= 1)
            v += __shfl_down(v, off, 64);
        if (lane == 0) bsum[r] = v;
    }
    __syncthreads();
    if (tid != 0) return;

    float tsum = 0.0f;
    for (int b = 0; b < 4; ++b)
        for (int c = 0; c < 4; ++c) {
            float S  = rowsum[b * NPART + c];
            float TP = rowsum[b * NPART + 4 + c];
            float CN = rowsum[b * NPART + 8 + c];
            float FP = S - TP;
            float FN = CN - TP;
            tsum += (TP + 1e-5f) / (TP + 0.3f * FP + 0.7f * FN + 1e-5f);
        }
    float l_dice = 1.0f - tsum / 16.0f;
    float l_main = (rowsum[12] + rowsum[NPART + 12] +
                    rowsum[2 * NPART + 12] + rowsum[3 * NPART + 12]) / (float)NVOX;
    float bs = 0.0f;
    for (int v = 0; v < NVOL; ++v) {
        int b = v / 3, c = (v % 3) + 1;
        float CN = rowsum[b * NPART + 8 + c];
        float contrib;
        if (CN <= 0.0f) contrib = 0.0f;
        else if (CN >= (float)SPATIAL) contrib = -rowsum[b * NPART + c] / (float)SPATIAL;
        else contrib = bsum[v] / (float)SPATIAL;
        bs += contrib;
    }
    float l_bound = bs / (12.0f + 1e-8f);
    out[0] = l_dice + l_main + 0.01f * l_bound;
}

extern "C" void kernel_launch(void* const* d_in, const int* in_sizes, int n_in,
                              void* d_out, int out_size, void* d_ws, size_t ws_size,
                              hipStream_t stream) {
    const float* preds = (const float*)d_in[0];
    const int* targets = (const int*)d_in[1];
    float* out = (float*)d_out;
    float* ws = (float*)d_ws;
    float* rpart = ws;                                  // 4*13*64 = 3328 floats
    float* bound = ws + 4 * NPART * 64;                 // 768 floats -> 4096 total
    unsigned int* dtp = (unsigned int*)(ws + 4096);     // 12 MB, 16B-aligned

    hipLaunchKernelGGL(dtxy_kernel, dim3(NBLK), dim3(512), 0, stream,
                       targets, dtp);
    hipLaunchKernelGGL(dtz_fused_kernel, dim3(NBLK), dim3(512), 0, stream,
                       dtp, preds, targets, bound, rpart);
    hipLaunchKernelGGL(final_kernel, dim3(1), dim3(256), 0, stream,
                       rpart, bound, out);
}